// Round 17
// baseline (210.952 us; speedup 1.0000x reference)
//
#include <hip/hip_runtime.h>
#include <hip/hip_bf16.h>

// Pipeline (no global atomics for data — they write through to HBM per-op;
// rounds 3/4). Build needs >=256 blocks / >=100K threads (rounds 5/7).
// Gathers are at the compulsory-miss x random-BW floor (~41MB FETCH, ~44us;
// r11-r13) — frozen. Round 17: (a) uint16-packed hist (2 nodes/int32 LDS
// atomic) -> NRANGE_H=2, halves hist edge re-reads in the fused dispatch;
// (b) dinv_scan+base fused via resident-grid flag barrier (49 blocks, all
// co-resident; atomicExch/atomicAdd(p,0) for cross-XCD coherence, flag
// zeroed by hipMemsetAsync). 7 -> 6 dispatches.

#define NCHUNK 32     // edge chunks
#define NRANGE_H 2    // hist node ranges (range = 25000, packed 2/int)
#define HISTP 12544   // packed ints (covers 25088 nodes)
#define NRANGE_B 4    // bin2 node ranges (range = 12500)
#define HIST_B2 12544

typedef __attribute__((ext_vector_type(8))) short bfrag;   // 8 bf16 = 4 VGPRs
typedef __attribute__((ext_vector_type(4))) float f32x4;

// ---------- MFMA 16-row wave tile: t = h@Wn (opt *dinv), agg = h@Wi + bias ----------
template <bool RELU, bool PRESCALE>
__device__ __forceinline__ void gemm_tile16(
    const float* h, const float* __restrict__ dinv,
    const short* Wn_f, const short* Wi_f, const float* b_s,
    __hip_bfloat16* __restrict__ t, float* agg, int r0, int lane, int N) {
  const int m = lane & 15;
  const int quad = lane >> 4;

  bfrag Bn[4][2], Bi[4][2];
#pragma unroll
  for (int ct = 0; ct < 4; ++ct)
#pragma unroll
    for (int kb = 0; kb < 2; ++kb) {
      Bn[ct][kb] = *(const bfrag*)&Wn_f[((ct * 2 + kb) * 64 + lane) * 8];
      Bi[ct][kb] = *(const bfrag*)&Wi_f[((ct * 2 + kb) * 64 + lane) * 8];
    }

  const int arow = r0 + m;
  bfrag A[2];
#pragma unroll
  for (int kb = 0; kb < 2; ++kb) {
    bfrag av = {};
    if (arow < N) {
      const float* src = &h[(size_t)arow * 64 + kb * 32 + quad * 8];
      float4 f0 = *(const float4*)src;
      float4 f1 = *(const float4*)(src + 4);
      float tmp[8] = {f0.x, f0.y, f0.z, f0.w, f1.x, f1.y, f1.z, f1.w};
#pragma unroll
      for (int j = 0; j < 8; ++j) {
        float v = RELU ? fmaxf(tmp[j], 0.f) : tmp[j];
        __hip_bfloat16 hb = __float2bfloat16(v);
        av[j] = *(short*)&hb;
      }
    }
    A[kb] = av;
  }

  f32x4 accT[4], accA[4];
#pragma unroll
  for (int ct = 0; ct < 4; ++ct) {
    f32x4 z = {0.f, 0.f, 0.f, 0.f};
    accT[ct] = z;
    accA[ct] = z;
  }
#pragma unroll
  for (int ct = 0; ct < 4; ++ct) {
    accT[ct] = __builtin_amdgcn_mfma_f32_16x16x32_bf16(A[0], Bn[ct][0], accT[ct], 0, 0, 0);
    accT[ct] = __builtin_amdgcn_mfma_f32_16x16x32_bf16(A[1], Bn[ct][1], accT[ct], 0, 0, 0);
    accA[ct] = __builtin_amdgcn_mfma_f32_16x16x32_bf16(A[0], Bi[ct][0], accA[ct], 0, 0, 0);
    accA[ct] = __builtin_amdgcn_mfma_f32_16x16x32_bf16(A[1], Bi[ct][1], accA[ct], 0, 0, 0);
  }

#pragma unroll
  for (int reg = 0; reg < 4; ++reg) {
    int r = r0 + quad * 4 + reg;
    if (r < N) {
      float dv = PRESCALE ? dinv[r] : 1.0f;
#pragma unroll
      for (int ct = 0; ct < 4; ++ct) {
        int col = ct * 16 + m;
        float tv = PRESCALE ? accT[ct][reg] * dv : accT[ct][reg];
        t[(size_t)r * 64 + col] = __float2bfloat16(tv);
        agg[(size_t)r * 64 + col] = accA[ct][reg] + b_s[col];
      }
    }
  }
}

__device__ __forceinline__ void stage_W_frag(const float* __restrict__ Wn,
                                             const float* __restrict__ Wi,
                                             short* Wn_f, short* Wi_f,
                                             int tid, int nthr) {
  for (int i = tid; i < 4096; i += nthr) {
    int k = i >> 6, n = i & 63;
    int dst = (((n >> 4) * 2 + (k >> 5)) * 64 + ((k >> 3) & 3) * 16 + (n & 15)) * 8 + (k & 7);
    __hip_bfloat16 a = __float2bfloat16(Wn[i]);
    __hip_bfloat16 b = __float2bfloat16(Wi[i]);
    Wn_f[dst] = *(short*)&a;
    Wi_f[dst] = *(short*)&b;
  }
}

// ---------- FUSED dispatch 1: layer-1 GEMM blocks + packed-hist blocks ----------
// blocks [0, gemmBlocks): GEMM (256 rows/block, 16 waves x 16-row tiles)
// blocks [gemmBlocks, +2*NRANGE_H*NCHUNK): uint16-packed partial histograms
__global__ __launch_bounds__(1024) void k_hist_gemm1(
    const int* __restrict__ ei, int* __restrict__ partial,
    const float* __restrict__ x,
    const float* __restrict__ Wn, const float* __restrict__ Wi,
    const float* __restrict__ bias,
    __hip_bfloat16* __restrict__ t, float* __restrict__ agg,
    int N, int E, int range, int gemmBlocks) {
  __shared__ __align__(16) char smem[HISTP * 4];   // 50 KB union: hist | W frags
  const int tid = threadIdx.x;

  if ((int)blockIdx.x < gemmBlocks) {
    short* Wn_f = (short*)smem;
    short* Wi_f = (short*)(smem + 8192);
    float* b_s = (float*)(smem + 16384);
    stage_W_frag(Wn, Wi, Wn_f, Wi_f, tid, 1024);
    if (tid < 64) b_s[tid] = bias[tid];
    __syncthreads();
    int w = tid >> 6;
    int lane = tid & 63;
    int r0 = blockIdx.x * 256 + w * 16;
    gemm_tile16<false, false>(x, nullptr, Wn_f, Wi_f, b_s, t, agg, r0, lane, N);
    return;
  }

  int* hist = (int*)smem;   // packed: node d at bits [(d&1)*16, +16) of hist[d>>1]
  int bid = blockIdx.x - gemmBlocks;
  int c = bid % NCHUNK;
  int r = (bid / NCHUNK) % NRANGE_H;
  int a = bid / (NCHUNK * NRANGE_H);
  const int* ids = ei + (size_t)a * E;
  int lo = r * range;
  int hi = min(N, lo + range);
  int len = hi - lo;
  int plen = (len + 1) >> 1;
  for (int i = tid; i < plen; i += 1024) hist[i] = 0;
  __syncthreads();
  int e0 = (int)((long long)E * c / NCHUNK);
  int e1 = (int)((long long)E * (c + 1) / NCHUNK);
  for (int e = e0 + tid; e < e1; e += 1024) {
    int id = ids[e];
    if (id >= lo && id < hi) {
      int d = id - lo;
      atomicAdd(&hist[d >> 1], 1 << ((d & 1) << 4));   // LDS atomic, packed
    }
  }
  __syncthreads();
  int* dst = partial + ((size_t)a * NCHUNK + c) * N + lo;
  for (int i = tid; i < len; i += 1024)
    dst[i] = (hist[i >> 1] >> ((i & 1) << 4)) & 0xFFFF;
}

// ---------- FUSED: dinv/indeg + exscan + base emission (resident-grid barrier) ----------
// nb blocks (<=64) are all co-resident (256 CUs) -> flag spin is safe.
// Cross-XCD coherence: bsum published via atomicExch+threadfence, read via
// device-scope atomicAdd(p,0). flag pre-zeroed by hipMemsetAsync.
__global__ __launch_bounds__(1024) void k_scan_base(
    const int* __restrict__ partial,
    float* __restrict__ dinv, int* __restrict__ indeg,
    int* __restrict__ ptr, int* __restrict__ base,
    int* __restrict__ bsum, int* __restrict__ flag, int N, int nb) {
  __shared__ int s[1024];
  __shared__ int pbs[64];
  const int tid = threadIdx.x;
  int g = blockIdx.x * 1024 + tid;
  int ind = 0;
  if (g < N) {
    int deg = 0;
#pragma unroll
    for (int c = 0; c < NCHUNK; ++c) {
      deg += partial[(size_t)c * N + g];
      ind += partial[((size_t)NCHUNK + c) * N + g];
    }
    dinv[g] = (deg > 0) ? (1.0f / sqrtf((float)deg)) : 0.0f;
    indeg[g] = ind;
  }
  s[tid] = ind;
  __syncthreads();
  for (int off = 1; off < 1024; off <<= 1) {
    int tv = (tid >= off) ? s[tid - off] : 0;
    __syncthreads();
    s[tid] += tv;
    __syncthreads();
  }
  int local = s[tid] - ind;          // block-local exclusive prefix (register)
  if (tid == 1023) {
    atomicExch(&bsum[blockIdx.x], s[1023]);
    __threadfence();
    atomicAdd(flag, 1);
  }
  if (tid == 0) {
    while (atomicAdd(flag, 0) < nb) __builtin_amdgcn_s_sleep(8);
    int acc = 0;
    for (int i = 0; i < nb; ++i) { pbs[i] = acc; acc += atomicAdd(&bsum[i], 0); }
  }
  __syncthreads();
  if (g < N) {
    int run = local + pbs[blockIdx.x];
    ptr[g] = run;
#pragma unroll
    for (int c = 0; c < NCHUNK; ++c) {
      base[(size_t)c * N + g] = run;
      run += partial[((size_t)NCHUNK + c) * N + g];
    }
  }
}

// ---------- counting-sort binning (LDS atomics on cnt; base from L2) ----------
__global__ __launch_bounds__(1024) void k_bin2(const int* __restrict__ ei,
                                               const int* __restrict__ base,
                                               int* __restrict__ csr_row,
                                               int N, int E, int range) {
  __shared__ int cnt[HIST_B2];   // 50 KB
  int c = blockIdx.x % NCHUNK;
  int r = blockIdx.x / NCHUNK;
  const int* row = ei;
  const int* col = ei + E;
  int lo = r * range;
  int hi = min(N, lo + range);
  int len = hi - lo;
  for (int i = threadIdx.x; i < len; i += 1024) cnt[i] = 0;
  __syncthreads();
  int e0 = (int)((long long)E * c / NCHUNK);
  int e1 = (int)((long long)E * (c + 1) / NCHUNK);
  const int* bslice = base + (size_t)c * N;
  for (int e = e0 + threadIdx.x; e < e1; e += 1024) {
    int cl = col[e];
    int rw = row[e];
    if (cl >= lo && cl < hi) {
      int off = atomicAdd(&cnt[cl - lo], 1);   // LDS atomic
      csr_row[bslice[cl] + off] = rw;          // base in L2; plain store
    }
  }
}

// ---------- standalone layer-2 MFMA dual GEMM (prescaled t2, relu on load) ----------
__global__ __launch_bounds__(256) void k_dual_gemm2(
    const float* h,            // aliases agg (in place)
    const float* __restrict__ Wn,
    const float* __restrict__ Wi,
    const float* __restrict__ bias,
    const float* __restrict__ dinv,
    __hip_bfloat16* __restrict__ t, float* agg, int N) {
  __shared__ short Wn_f[4096];
  __shared__ short Wi_f[4096];
  __shared__ float b_s[64];
  const int tid = threadIdx.x;
  stage_W_frag(Wn, Wi, Wn_f, Wi_f, tid, 256);
  if (tid < 64) b_s[tid] = bias[tid];
  __syncthreads();
  int w = tid >> 6;
  int lane = tid & 63;
  int r0 = blockIdx.x * 64 + w * 16;
  gemm_tile16<true, true>(h, dinv, Wn_f, Wi_f, b_s, t, agg, r0, lane, N);
}

// ---------- CSR gather (layer 1, r10 form): agg[n] += t[ra]*dinv[ra]*dinv[n] ----------
__global__ __launch_bounds__(256) void k_gather(
    const int* __restrict__ csr_row, const int* __restrict__ ptr,
    const int* __restrict__ indeg, const float* __restrict__ dinv,
    const __hip_bfloat16* __restrict__ t, float* __restrict__ agg, int N) {
  int n = blockIdx.x * 4 + (threadIdx.x >> 6);
  if (n >= N) return;
  int lane = threadIdx.x & 63;
  int q = lane >> 4;
  int fl = lane & 15;
  int i0 = ptr[n];
  int end = i0 + indeg[n];
  float dn = dinv[n];

  float4 aggv = make_float4(0.f, 0.f, 0.f, 0.f);
  if (q == 0) aggv = *(const float4*)&agg[(size_t)n * 64 + 4 * fl];

  float4 acc = make_float4(0.f, 0.f, 0.f, 0.f);
  int i = i0 + q;
  for (; i + 4 < end; i += 8) {
    int ra = csr_row[i];
    int rb = csr_row[i + 4];
    float na = dinv[ra];
    float nb = dinv[rb];
    ushort4 ua = *(const ushort4*)&t[(size_t)ra * 64 + 4 * fl];
    ushort4 ub = *(const ushort4*)&t[(size_t)rb * 64 + 4 * fl];
    float4 va, vb;
    ((unsigned*)&va)[0] = (unsigned)ua.x << 16; ((unsigned*)&va)[1] = (unsigned)ua.y << 16;
    ((unsigned*)&va)[2] = (unsigned)ua.z << 16; ((unsigned*)&va)[3] = (unsigned)ua.w << 16;
    ((unsigned*)&vb)[0] = (unsigned)ub.x << 16; ((unsigned*)&vb)[1] = (unsigned)ub.y << 16;
    ((unsigned*)&vb)[2] = (unsigned)ub.z << 16; ((unsigned*)&vb)[3] = (unsigned)ub.w << 16;
    acc.x = fmaf(va.x, na, acc.x); acc.y = fmaf(va.y, na, acc.y);
    acc.z = fmaf(va.z, na, acc.z); acc.w = fmaf(va.w, na, acc.w);
    acc.x = fmaf(vb.x, nb, acc.x); acc.y = fmaf(vb.y, nb, acc.y);
    acc.z = fmaf(vb.z, nb, acc.z); acc.w = fmaf(vb.w, nb, acc.w);
  }
  for (; i < end; i += 4) {
    int ra = csr_row[i];
    float na = dinv[ra];
    ushort4 ua = *(const ushort4*)&t[(size_t)ra * 64 + 4 * fl];
    float4 va;
    ((unsigned*)&va)[0] = (unsigned)ua.x << 16; ((unsigned*)&va)[1] = (unsigned)ua.y << 16;
    ((unsigned*)&va)[2] = (unsigned)ua.z << 16; ((unsigned*)&va)[3] = (unsigned)ua.w << 16;
    acc.x = fmaf(va.x, na, acc.x); acc.y = fmaf(va.y, na, acc.y);
    acc.z = fmaf(va.z, na, acc.z); acc.w = fmaf(va.w, na, acc.w);
  }
  acc.x += __shfl_xor(acc.x, 16); acc.y += __shfl_xor(acc.y, 16);
  acc.z += __shfl_xor(acc.z, 16); acc.w += __shfl_xor(acc.w, 16);
  acc.x += __shfl_xor(acc.x, 32); acc.y += __shfl_xor(acc.y, 32);
  acc.z += __shfl_xor(acc.z, 32); acc.w += __shfl_xor(acc.w, 32);
  if (q == 0) {
    aggv.x += dn * acc.x; aggv.y += dn * acc.y;
    aggv.z += dn * acc.z; aggv.w += dn * acc.w;
    *(float4*)&agg[(size_t)n * 64 + 4 * fl] = aggv;
  }
}

// ---------- FUSED layer-2 gather + output GEMM (t2 prescaled: pure-add) ----------
__global__ __launch_bounds__(256) void k_gather_out(
    const int* __restrict__ csr_row, const int* __restrict__ ptr,
    const int* __restrict__ indeg, const float* __restrict__ dinv,
    const __hip_bfloat16* __restrict__ t, const float* __restrict__ agg,
    const float* __restrict__ Wo,   // [64,32]
    const float* __restrict__ bo,   // [32]
    float* __restrict__ out, int N) {
  __shared__ float Wo_s[64 * 32];
  __shared__ float bo_s[32];
  __shared__ float rowbuf[4][64];

  const int tid = threadIdx.x;
  for (int i = tid; i < 2048; i += 256) Wo_s[i] = Wo[i];
  if (tid < 32) bo_s[tid] = bo[tid];
  __syncthreads();   // barrier BEFORE any divergent exit

  int w = tid >> 6;
  int n = blockIdx.x * 4 + w;
  if (n >= N) return;
  int lane = tid & 63;
  int q = lane >> 4;
  int fl = lane & 15;
  int i0 = ptr[n];
  int end = i0 + indeg[n];
  float dn = dinv[n];

  float4 aggv = make_float4(0.f, 0.f, 0.f, 0.f);
  if (q == 0) aggv = *(const float4*)&agg[(size_t)n * 64 + 4 * fl];

  float4 acc = make_float4(0.f, 0.f, 0.f, 0.f);
  int i = i0 + q;
  for (; i + 4 < end; i += 8) {
    int ra = csr_row[i];
    int rb = csr_row[i + 4];
    ushort4 ua = *(const ushort4*)&t[(size_t)ra * 64 + 4 * fl];
    ushort4 ub = *(const ushort4*)&t[(size_t)rb * 64 + 4 * fl];
    float4 va, vb;
    ((unsigned*)&va)[0] = (unsigned)ua.x << 16; ((unsigned*)&va)[1] = (unsigned)ua.y << 16;
    ((unsigned*)&va)[2] = (unsigned)ua.z << 16; ((unsigned*)&va)[3] = (unsigned)ua.w << 16;
    ((unsigned*)&vb)[0] = (unsigned)ub.x << 16; ((unsigned*)&vb)[1] = (unsigned)ub.y << 16;
    ((unsigned*)&vb)[2] = (unsigned)ub.z << 16; ((unsigned*)&vb)[3] = (unsigned)ub.w << 16;
    acc.x += va.x + vb.x; acc.y += va.y + vb.y;
    acc.z += va.z + vb.z; acc.w += va.w + vb.w;
  }
  for (; i < end; i += 4) {
    int ra = csr_row[i];
    ushort4 ua = *(const ushort4*)&t[(size_t)ra * 64 + 4 * fl];
    float4 va;
    ((unsigned*)&va)[0] = (unsigned)ua.x << 16; ((unsigned*)&va)[1] = (unsigned)ua.y << 16;
    ((unsigned*)&va)[2] = (unsigned)ua.z << 16; ((unsigned*)&va)[3] = (unsigned)ua.w << 16;
    acc.x += va.x; acc.y += va.y; acc.z += va.z; acc.w += va.w;
  }
  acc.x += __shfl_xor(acc.x, 16); acc.y += __shfl_xor(acc.y, 16);
  acc.z += __shfl_xor(acc.z, 16); acc.w += __shfl_xor(acc.w, 16);
  acc.x += __shfl_xor(acc.x, 32); acc.y += __shfl_xor(acc.y, 32);
  acc.z += __shfl_xor(acc.z, 32); acc.w += __shfl_xor(acc.w, 32);
  if (q == 0) {
    rowbuf[w][4 * fl + 0] = fmaxf(aggv.x + dn * acc.x, 0.f);
    rowbuf[w][4 * fl + 1] = fmaxf(aggv.y + dn * acc.y, 0.f);
    rowbuf[w][4 * fl + 2] = fmaxf(aggv.z + dn * acc.z, 0.f);
    rowbuf[w][4 * fl + 3] = fmaxf(aggv.w + dn * acc.w, 0.f);
  }
  // same-wave LDS RAW: compiler inserts lgkmcnt wait; no barrier needed.
  int half = lane >> 5;
  int j = lane & 31;
  float ov = 0.f;
#pragma unroll 8
  for (int k = 32 * half; k < 32 * half + 32; ++k)
    ov = fmaf(rowbuf[w][k], Wo_s[k * 32 + j], ov);
  ov += __shfl_xor(ov, 32);
  if (half == 0) out[(size_t)n * 32 + j] = ov + bo_s[j];
}

extern "C" void kernel_launch(void* const* d_in, const int* in_sizes, int n_in,
                              void* d_out, int out_size, void* d_ws, size_t ws_size,
                              hipStream_t stream) {
  const float* x = (const float*)d_in[0];
  const int* ei = (const int*)d_in[1];
  const float* W_in1 = (const float*)d_in[2];
  const float* W_neigh1 = (const float*)d_in[3];
  const float* bias1 = (const float*)d_in[4];
  const float* W_in2 = (const float*)d_in[5];
  const float* W_neigh2 = (const float*)d_in[6];
  const float* bias2 = (const float*)d_in[7];
  const float* W_out = (const float*)d_in[8];
  const float* b_out = (const float*)d_in[9];
  float* out = (float*)d_out;

  const int N = in_sizes[0] / 64;
  const int E = in_sizes[1] / 2;

  char* ws = (char*)d_ws;
  size_t off = 0;
  auto alloc = [&](size_t bytes) -> void* {
    void* p = ws + off;
    off += (bytes + 255) & ~(size_t)255;
    return p;
  };
  float* dinv = (float*)alloc((size_t)N * 4);
  int* indeg = (int*)alloc((size_t)N * 4);
  int* ptr = (int*)alloc((size_t)N * 4);
  int* bsum = (int*)alloc(256);
  int* flag = (int*)alloc(256);
  int* csr_row = (int*)alloc((size_t)E * 4);
  int* partial = (int*)alloc((size_t)2 * NCHUNK * N * 4);
  int* base = (int*)alloc((size_t)NCHUNK * N * 4);
  __hip_bfloat16* t = (__hip_bfloat16*)alloc((size_t)N * 64 * 2);
  float* agg = (float*)alloc((size_t)N * 64 * 4);
  (void)ws_size;

  int range_h = (N + NRANGE_H - 1) / NRANGE_H;  // 25000 <= 2*HISTP
  int range_b = (N + NRANGE_B - 1) / NRANGE_B;  // 12500 <= HIST_B2
  int gRows = (N + 63) / 64;
  int gNode = (N + 3) / 4;
  int nb = (N + 1023) / 1024;                   // 49 <= 64 (pbs/bsum cap)
  int gemmBlocks = (N + 255) / 256;

  hipMemsetAsync(flag, 0, 4, stream);

  // dispatch 1: layer-1 GEMM (independent of build) fused with packed hists
  k_hist_gemm1<<<gemmBlocks + 2 * NRANGE_H * NCHUNK, 1024, 0, stream>>>(
      ei, partial, x, W_neigh1, W_in1, bias1, t, agg, N, E, range_h, gemmBlocks);

  // dispatch 2: dinv + indeg + global exscan + base (resident-grid barrier)
  k_scan_base<<<nb, 1024, 0, stream>>>(partial, dinv, indeg, ptr, base, bsum, flag, N, nb);

  // dispatch 3: counting-sort binning
  k_bin2<<<NRANGE_B * NCHUNK, 1024, 0, stream>>>(ei, base, csr_row, N, E, range_b);

  // layer-1 gather (per-edge dinv[ra], r10 form)
  k_gather<<<gNode, 256, 0, stream>>>(csr_row, ptr, indeg, dinv, t, agg, N);

  // layer 2 (MFMA, in-place on agg, prescaled t2), then fused gather+output
  k_dual_gemm2<<<gRows, 256, 0, stream>>>(agg, W_neigh2, W_in2, bias2, dinv, t, agg, N);
  k_gather_out<<<gNode, 256, 0, stream>>>(csr_row, ptr, indeg, dinv, t, agg,
                                          W_out, b_out, out, N);
}

// Round 18
// 200.208 us; speedup vs baseline: 1.0537x; 1.0537x over previous
//
#include <hip/hip_runtime.h>
#include <hip/hip_bf16.h>

// Pipeline (no global atomics — write through to HBM per-op; rounds 3/4).
// Build needs >=256 blocks / >=100K threads (rounds 5/7). Gathers are at the
// compulsory-miss x random-BW floor (~41MB FETCH, ~44us; r11-r13). Round 16
// (BEST, 198.6us): layer-1 GEMM build-independent (no dinv prescale on t1;
// gather-1 uses per-edge dinv[ra]) and FUSED into the k_hist dispatch via a
// block-range branch. Round-17 lessons (packed hist: 2x LDS-atomic aliasing;
// resident-grid barrier scan: serialized spin) both REGRESSED — reverted.

#define NCHUNK 32     // edge chunks
#define NRANGE_H 4    // hist node ranges (range = 12500)
#define HIST_H 12544
#define NRANGE_B 4    // bin2 node ranges (range = 12500)
#define HIST_B2 12544

typedef __attribute__((ext_vector_type(8))) short bfrag;   // 8 bf16 = 4 VGPRs
typedef __attribute__((ext_vector_type(4))) float f32x4;

// ---------- MFMA 16-row wave tile: t = h@Wn (opt *dinv), agg = h@Wi + bias ----------
// W LDS layout is FRAGMENT ORDER: frag (ct,kb) at shorts [((ct*2+kb)*64+lane)*8].
template <bool RELU, bool PRESCALE>
__device__ __forceinline__ void gemm_tile16(
    const float* h, const float* __restrict__ dinv,
    const short* Wn_f, const short* Wi_f, const float* b_s,
    __hip_bfloat16* __restrict__ t, float* agg, int r0, int lane, int N) {
  const int m = lane & 15;
  const int quad = lane >> 4;

  bfrag Bn[4][2], Bi[4][2];
#pragma unroll
  for (int ct = 0; ct < 4; ++ct)
#pragma unroll
    for (int kb = 0; kb < 2; ++kb) {
      Bn[ct][kb] = *(const bfrag*)&Wn_f[((ct * 2 + kb) * 64 + lane) * 8];
      Bi[ct][kb] = *(const bfrag*)&Wi_f[((ct * 2 + kb) * 64 + lane) * 8];
    }

  const int arow = r0 + m;
  bfrag A[2];
#pragma unroll
  for (int kb = 0; kb < 2; ++kb) {
    bfrag av = {};
    if (arow < N) {
      const float* src = &h[(size_t)arow * 64 + kb * 32 + quad * 8];
      float4 f0 = *(const float4*)src;
      float4 f1 = *(const float4*)(src + 4);
      float tmp[8] = {f0.x, f0.y, f0.z, f0.w, f1.x, f1.y, f1.z, f1.w};
#pragma unroll
      for (int j = 0; j < 8; ++j) {
        float v = RELU ? fmaxf(tmp[j], 0.f) : tmp[j];
        __hip_bfloat16 hb = __float2bfloat16(v);
        av[j] = *(short*)&hb;
      }
    }
    A[kb] = av;
  }

  f32x4 accT[4], accA[4];
#pragma unroll
  for (int ct = 0; ct < 4; ++ct) {
    f32x4 z = {0.f, 0.f, 0.f, 0.f};
    accT[ct] = z;
    accA[ct] = z;
  }
#pragma unroll
  for (int ct = 0; ct < 4; ++ct) {
    accT[ct] = __builtin_amdgcn_mfma_f32_16x16x32_bf16(A[0], Bn[ct][0], accT[ct], 0, 0, 0);
    accT[ct] = __builtin_amdgcn_mfma_f32_16x16x32_bf16(A[1], Bn[ct][1], accT[ct], 0, 0, 0);
    accA[ct] = __builtin_amdgcn_mfma_f32_16x16x32_bf16(A[0], Bi[ct][0], accA[ct], 0, 0, 0);
    accA[ct] = __builtin_amdgcn_mfma_f32_16x16x32_bf16(A[1], Bi[ct][1], accA[ct], 0, 0, 0);
  }

#pragma unroll
  for (int reg = 0; reg < 4; ++reg) {
    int r = r0 + quad * 4 + reg;
    if (r < N) {
      float dv = PRESCALE ? dinv[r] : 1.0f;
#pragma unroll
      for (int ct = 0; ct < 4; ++ct) {
        int col = ct * 16 + m;
        float tv = PRESCALE ? accT[ct][reg] * dv : accT[ct][reg];
        t[(size_t)r * 64 + col] = __float2bfloat16(tv);
        agg[(size_t)r * 64 + col] = accA[ct][reg] + b_s[col];
      }
    }
  }
}

// W staging in fragment order (256 or 1024 threads)
__device__ __forceinline__ void stage_W_frag(const float* __restrict__ Wn,
                                             const float* __restrict__ Wi,
                                             short* Wn_f, short* Wi_f,
                                             int tid, int nthr) {
  for (int i = tid; i < 4096; i += nthr) {
    int k = i >> 6, n = i & 63;
    int dst = (((n >> 4) * 2 + (k >> 5)) * 64 + ((k >> 3) & 3) * 16 + (n & 15)) * 8 + (k & 7);
    __hip_bfloat16 a = __float2bfloat16(Wn[i]);
    __hip_bfloat16 b = __float2bfloat16(Wi[i]);
    Wn_f[dst] = *(short*)&a;
    Wi_f[dst] = *(short*)&b;
  }
}

// ---------- FUSED dispatch 1: layer-1 GEMM blocks + histogram blocks ----------
// blocks [0, gemmBlocks): GEMM (256 rows/block, 16 waves x 16-row tiles)
// blocks [gemmBlocks, +2*NRANGE_H*NCHUNK): partial histograms
__global__ __launch_bounds__(1024) void k_hist_gemm1(
    const int* __restrict__ ei, int* __restrict__ partial,
    const float* __restrict__ x,
    const float* __restrict__ Wn, const float* __restrict__ Wi,
    const float* __restrict__ bias,
    __hip_bfloat16* __restrict__ t, float* __restrict__ agg,
    int N, int E, int range, int gemmBlocks) {
  __shared__ __align__(16) char smem[HIST_H * 4];   // union: hist | W frags
  const int tid = threadIdx.x;

  if ((int)blockIdx.x < gemmBlocks) {
    short* Wn_f = (short*)smem;                     // 8192 B
    short* Wi_f = (short*)(smem + 8192);            // 8192 B
    float* b_s = (float*)(smem + 16384);            // 256 B
    stage_W_frag(Wn, Wi, Wn_f, Wi_f, tid, 1024);
    if (tid < 64) b_s[tid] = bias[tid];
    __syncthreads();
    int w = tid >> 6;
    int lane = tid & 63;
    int r0 = blockIdx.x * 256 + w * 16;
    gemm_tile16<false, false>(x, nullptr, Wn_f, Wi_f, b_s, t, agg, r0, lane, N);
    return;
  }

  int* hist = (int*)smem;
  int bid = blockIdx.x - gemmBlocks;
  int c = bid % NCHUNK;
  int r = (bid / NCHUNK) % NRANGE_H;
  int a = bid / (NCHUNK * NRANGE_H);
  const int* ids = ei + (size_t)a * E;
  int lo = r * range;
  int hi = min(N, lo + range);
  int len = hi - lo;
  for (int i = tid; i < len; i += 1024) hist[i] = 0;
  __syncthreads();
  int e0 = (int)((long long)E * c / NCHUNK);
  int e1 = (int)((long long)E * (c + 1) / NCHUNK);
  for (int e = e0 + tid; e < e1; e += 1024) {
    int id = ids[e];
    if (id >= lo && id < hi) atomicAdd(&hist[id - lo], 1);  // LDS atomic
  }
  __syncthreads();
  int* dst = partial + ((size_t)a * NCHUNK + c) * N + lo;
  for (int i = tid; i < len; i += 1024) dst[i] = hist[i];
}

// ---------- fused: reduce partials -> dinv/indeg, then in-block exscan ----------
__global__ __launch_bounds__(1024) void k_dinv_scan(const int* __restrict__ partial,
                                                    float* __restrict__ dinv,
                                                    int* __restrict__ indeg,
                                                    int* __restrict__ ptr,
                                                    int* __restrict__ bsum, int N) {
  __shared__ int s[1024];
  int g = blockIdx.x * 1024 + threadIdx.x;
  int deg = 0, ind = 0;
  if (g < N) {
#pragma unroll
    for (int c = 0; c < NCHUNK; ++c) {
      deg += partial[(size_t)c * N + g];
      ind += partial[((size_t)NCHUNK + c) * N + g];
    }
    dinv[g] = (deg > 0) ? (1.0f / sqrtf((float)deg)) : 0.0f;
    indeg[g] = ind;
  }
  s[threadIdx.x] = ind;
  __syncthreads();
  for (int off = 1; off < 1024; off <<= 1) {
    int tv = (threadIdx.x >= off) ? s[threadIdx.x - off] : 0;
    __syncthreads();
    s[threadIdx.x] += tv;
    __syncthreads();
  }
  if (g < N) ptr[g] = s[threadIdx.x] - ind;  // exclusive within block
  if (threadIdx.x == 1023) bsum[blockIdx.x] = s[1023];
}

// ---------- fused: scan bsum (in LDS) + finalize ptr + emit bases ----------
__global__ __launch_bounds__(256) void k_base(const int* __restrict__ partial,
                                              const int* __restrict__ bsum,
                                              int* __restrict__ ptr,
                                              int* __restrict__ base, int N, int nb) {
  __shared__ int pbs[64];
  if (threadIdx.x == 0) {
    int acc = 0;
    for (int i = 0; i < nb; ++i) { pbs[i] = acc; acc += bsum[i]; }
  }
  __syncthreads();
  int n = blockIdx.x * 256 + threadIdx.x;
  if (n >= N) return;
  int run = ptr[n] + pbs[n >> 10];
  ptr[n] = run;                      // final global exclusive scan
#pragma unroll
  for (int c = 0; c < NCHUNK; ++c) {
    base[(size_t)c * N + n] = run;
    run += partial[((size_t)NCHUNK + c) * N + n];
  }
}

// ---------- counting-sort binning (LDS atomics on cnt; base from L2) ----------
__global__ __launch_bounds__(1024) void k_bin2(const int* __restrict__ ei,
                                               const int* __restrict__ base,
                                               int* __restrict__ csr_row,
                                               int N, int E, int range) {
  __shared__ int cnt[HIST_B2];   // 50 KB
  int c = blockIdx.x % NCHUNK;
  int r = blockIdx.x / NCHUNK;
  const int* row = ei;
  const int* col = ei + E;
  int lo = r * range;
  int hi = min(N, lo + range);
  int len = hi - lo;
  for (int i = threadIdx.x; i < len; i += 1024) cnt[i] = 0;
  __syncthreads();
  int e0 = (int)((long long)E * c / NCHUNK);
  int e1 = (int)((long long)E * (c + 1) / NCHUNK);
  const int* bslice = base + (size_t)c * N;
  for (int e = e0 + threadIdx.x; e < e1; e += 1024) {
    int cl = col[e];
    int rw = row[e];
    if (cl >= lo && cl < hi) {
      int off = atomicAdd(&cnt[cl - lo], 1);   // LDS atomic
      csr_row[bslice[cl] + off] = rw;          // base in L2; plain store
    }
  }
}

// ---------- standalone layer-2 MFMA dual GEMM (prescaled t2, relu on load) ----------
__global__ __launch_bounds__(256) void k_dual_gemm2(
    const float* h,            // aliases agg (in place)
    const float* __restrict__ Wn,
    const float* __restrict__ Wi,
    const float* __restrict__ bias,
    const float* __restrict__ dinv,
    __hip_bfloat16* __restrict__ t, float* agg, int N) {
  __shared__ short Wn_f[4096];
  __shared__ short Wi_f[4096];
  __shared__ float b_s[64];
  const int tid = threadIdx.x;
  stage_W_frag(Wn, Wi, Wn_f, Wi_f, tid, 256);
  if (tid < 64) b_s[tid] = bias[tid];
  __syncthreads();
  int w = tid >> 6;
  int lane = tid & 63;
  int r0 = blockIdx.x * 64 + w * 16;
  gemm_tile16<true, true>(h, dinv, Wn_f, Wi_f, b_s, t, agg, r0, lane, N);
}

// ---------- CSR gather (layer 1, r10 form): agg[n] += t[ra]*dinv[ra]*dinv[n] ----------
__global__ __launch_bounds__(256) void k_gather(
    const int* __restrict__ csr_row, const int* __restrict__ ptr,
    const int* __restrict__ indeg, const float* __restrict__ dinv,
    const __hip_bfloat16* __restrict__ t, float* __restrict__ agg, int N) {
  int n = blockIdx.x * 4 + (threadIdx.x >> 6);
  if (n >= N) return;
  int lane = threadIdx.x & 63;
  int q = lane >> 4;
  int fl = lane & 15;
  int i0 = ptr[n];
  int end = i0 + indeg[n];
  float dn = dinv[n];

  float4 aggv = make_float4(0.f, 0.f, 0.f, 0.f);
  if (q == 0) aggv = *(const float4*)&agg[(size_t)n * 64 + 4 * fl];

  float4 acc = make_float4(0.f, 0.f, 0.f, 0.f);
  int i = i0 + q;
  for (; i + 4 < end; i += 8) {
    int ra = csr_row[i];
    int rb = csr_row[i + 4];
    float na = dinv[ra];
    float nb = dinv[rb];
    ushort4 ua = *(const ushort4*)&t[(size_t)ra * 64 + 4 * fl];
    ushort4 ub = *(const ushort4*)&t[(size_t)rb * 64 + 4 * fl];
    float4 va, vb;
    ((unsigned*)&va)[0] = (unsigned)ua.x << 16; ((unsigned*)&va)[1] = (unsigned)ua.y << 16;
    ((unsigned*)&va)[2] = (unsigned)ua.z << 16; ((unsigned*)&va)[3] = (unsigned)ua.w << 16;
    ((unsigned*)&vb)[0] = (unsigned)ub.x << 16; ((unsigned*)&vb)[1] = (unsigned)ub.y << 16;
    ((unsigned*)&vb)[2] = (unsigned)ub.z << 16; ((unsigned*)&vb)[3] = (unsigned)ub.w << 16;
    acc.x = fmaf(va.x, na, acc.x); acc.y = fmaf(va.y, na, acc.y);
    acc.z = fmaf(va.z, na, acc.z); acc.w = fmaf(va.w, na, acc.w);
    acc.x = fmaf(vb.x, nb, acc.x); acc.y = fmaf(vb.y, nb, acc.y);
    acc.z = fmaf(vb.z, nb, acc.z); acc.w = fmaf(vb.w, nb, acc.w);
  }
  for (; i < end; i += 4) {
    int ra = csr_row[i];
    float na = dinv[ra];
    ushort4 ua = *(const ushort4*)&t[(size_t)ra * 64 + 4 * fl];
    float4 va;
    ((unsigned*)&va)[0] = (unsigned)ua.x << 16; ((unsigned*)&va)[1] = (unsigned)ua.y << 16;
    ((unsigned*)&va)[2] = (unsigned)ua.z << 16; ((unsigned*)&va)[3] = (unsigned)ua.w << 16;
    acc.x = fmaf(va.x, na, acc.x); acc.y = fmaf(va.y, na, acc.y);
    acc.z = fmaf(va.z, na, acc.z); acc.w = fmaf(va.w, na, acc.w);
  }
  acc.x += __shfl_xor(acc.x, 16); acc.y += __shfl_xor(acc.y, 16);
  acc.z += __shfl_xor(acc.z, 16); acc.w += __shfl_xor(acc.w, 16);
  acc.x += __shfl_xor(acc.x, 32); acc.y += __shfl_xor(acc.y, 32);
  acc.z += __shfl_xor(acc.z, 32); acc.w += __shfl_xor(acc.w, 32);
  if (q == 0) {
    aggv.x += dn * acc.x; aggv.y += dn * acc.y;
    aggv.z += dn * acc.z; aggv.w += dn * acc.w;
    *(float4*)&agg[(size_t)n * 64 + 4 * fl] = aggv;
  }
}

// ---------- FUSED layer-2 gather + output GEMM (t2 prescaled: pure-add) ----------
__global__ __launch_bounds__(256) void k_gather_out(
    const int* __restrict__ csr_row, const int* __restrict__ ptr,
    const int* __restrict__ indeg, const float* __restrict__ dinv,
    const __hip_bfloat16* __restrict__ t, const float* __restrict__ agg,
    const float* __restrict__ Wo,   // [64,32]
    const float* __restrict__ bo,   // [32]
    float* __restrict__ out, int N) {
  __shared__ float Wo_s[64 * 32];
  __shared__ float bo_s[32];
  __shared__ float rowbuf[4][64];

  const int tid = threadIdx.x;
  for (int i = tid; i < 2048; i += 256) Wo_s[i] = Wo[i];
  if (tid < 32) bo_s[tid] = bo[tid];
  __syncthreads();   // barrier BEFORE any divergent exit

  int w = tid >> 6;
  int n = blockIdx.x * 4 + w;
  if (n >= N) return;
  int lane = tid & 63;
  int q = lane >> 4;
  int fl = lane & 15;
  int i0 = ptr[n];
  int end = i0 + indeg[n];
  float dn = dinv[n];

  float4 aggv = make_float4(0.f, 0.f, 0.f, 0.f);
  if (q == 0) aggv = *(const float4*)&agg[(size_t)n * 64 + 4 * fl];

  float4 acc = make_float4(0.f, 0.f, 0.f, 0.f);
  int i = i0 + q;
  for (; i + 4 < end; i += 8) {
    int ra = csr_row[i];
    int rb = csr_row[i + 4];
    ushort4 ua = *(const ushort4*)&t[(size_t)ra * 64 + 4 * fl];
    ushort4 ub = *(const ushort4*)&t[(size_t)rb * 64 + 4 * fl];
    float4 va, vb;
    ((unsigned*)&va)[0] = (unsigned)ua.x << 16; ((unsigned*)&va)[1] = (unsigned)ua.y << 16;
    ((unsigned*)&va)[2] = (unsigned)ua.z << 16; ((unsigned*)&va)[3] = (unsigned)ua.w << 16;
    ((unsigned*)&vb)[0] = (unsigned)ub.x << 16; ((unsigned*)&vb)[1] = (unsigned)ub.y << 16;
    ((unsigned*)&vb)[2] = (unsigned)ub.z << 16; ((unsigned*)&vb)[3] = (unsigned)ub.w << 16;
    acc.x += va.x + vb.x; acc.y += va.y + vb.y;
    acc.z += va.z + vb.z; acc.w += va.w + vb.w;
  }
  for (; i < end; i += 4) {
    int ra = csr_row[i];
    ushort4 ua = *(const ushort4*)&t[(size_t)ra * 64 + 4 * fl];
    float4 va;
    ((unsigned*)&va)[0] = (unsigned)ua.x << 16; ((unsigned*)&va)[1] = (unsigned)ua.y << 16;
    ((unsigned*)&va)[2] = (unsigned)ua.z << 16; ((unsigned*)&va)[3] = (unsigned)ua.w << 16;
    acc.x += va.x; acc.y += va.y; acc.z += va.z; acc.w += va.w;
  }
  acc.x += __shfl_xor(acc.x, 16); acc.y += __shfl_xor(acc.y, 16);
  acc.z += __shfl_xor(acc.z, 16); acc.w += __shfl_xor(acc.w, 16);
  acc.x += __shfl_xor(acc.x, 32); acc.y += __shfl_xor(acc.y, 32);
  acc.z += __shfl_xor(acc.z, 32); acc.w += __shfl_xor(acc.w, 32);
  if (q == 0) {
    rowbuf[w][4 * fl + 0] = fmaxf(aggv.x + dn * acc.x, 0.f);
    rowbuf[w][4 * fl + 1] = fmaxf(aggv.y + dn * acc.y, 0.f);
    rowbuf[w][4 * fl + 2] = fmaxf(aggv.z + dn * acc.z, 0.f);
    rowbuf[w][4 * fl + 3] = fmaxf(aggv.w + dn * acc.w, 0.f);
  }
  // same-wave LDS RAW: compiler inserts lgkmcnt wait; no barrier needed.
  int half = lane >> 5;
  int j = lane & 31;
  float ov = 0.f;
#pragma unroll 8
  for (int k = 32 * half; k < 32 * half + 32; ++k)
    ov = fmaf(rowbuf[w][k], Wo_s[k * 32 + j], ov);
  ov += __shfl_xor(ov, 32);
  if (half == 0) out[(size_t)n * 32 + j] = ov + bo_s[j];
}

extern "C" void kernel_launch(void* const* d_in, const int* in_sizes, int n_in,
                              void* d_out, int out_size, void* d_ws, size_t ws_size,
                              hipStream_t stream) {
  const float* x = (const float*)d_in[0];
  const int* ei = (const int*)d_in[1];
  const float* W_in1 = (const float*)d_in[2];
  const float* W_neigh1 = (const float*)d_in[3];
  const float* bias1 = (const float*)d_in[4];
  const float* W_in2 = (const float*)d_in[5];
  const float* W_neigh2 = (const float*)d_in[6];
  const float* bias2 = (const float*)d_in[7];
  const float* W_out = (const float*)d_in[8];
  const float* b_out = (const float*)d_in[9];
  float* out = (float*)d_out;

  const int N = in_sizes[0] / 64;
  const int E = in_sizes[1] / 2;

  char* ws = (char*)d_ws;
  size_t off = 0;
  auto alloc = [&](size_t bytes) -> void* {
    void* p = ws + off;
    off += (bytes + 255) & ~(size_t)255;
    return p;
  };
  float* dinv = (float*)alloc((size_t)N * 4);
  int* indeg = (int*)alloc((size_t)N * 4);
  int* ptr = (int*)alloc((size_t)N * 4);
  int* bsum = (int*)alloc(256);
  int* csr_row = (int*)alloc((size_t)E * 4);
  int* partial = (int*)alloc((size_t)2 * NCHUNK * N * 4);
  int* base = (int*)alloc((size_t)NCHUNK * N * 4);
  __hip_bfloat16* t = (__hip_bfloat16*)alloc((size_t)N * 64 * 2);
  float* agg = (float*)alloc((size_t)N * 64 * 4);
  (void)ws_size;

  int range_h = (N + NRANGE_H - 1) / NRANGE_H;  // 12500 <= HIST_H
  int range_b = (N + NRANGE_B - 1) / NRANGE_B;  // 12500 <= HIST_B2
  int gN = (N + 255) / 256;
  int gRows = (N + 63) / 64;
  int gNode = (N + 3) / 4;
  int nb = (N + 1023) / 1024;
  int gemmBlocks = (N + 255) / 256;             // 256 rows per 1024-thread block

  // dispatch 1: layer-1 GEMM (independent of build) fused with histograms
  k_hist_gemm1<<<gemmBlocks + 2 * NRANGE_H * NCHUNK, 1024, 0, stream>>>(
      ei, partial, x, W_neigh1, W_in1, bias1, t, agg, N, E, range_h, gemmBlocks);
  k_dinv_scan<<<nb, 1024, 0, stream>>>(partial, dinv, indeg, ptr, bsum, N);
  k_base<<<gN, 256, 0, stream>>>(partial, bsum, ptr, base, N, nb);
  k_bin2<<<NRANGE_B * NCHUNK, 1024, 0, stream>>>(ei, base, csr_row, N, E, range_b);

  // layer-1 gather (per-edge dinv[ra], r10 form)
  k_gather<<<gNode, 256, 0, stream>>>(csr_row, ptr, indeg, dinv, t, agg, N);

  // layer 2 (MFMA, in-place on agg, prescaled t2), then fused gather+output
  k_dual_gemm2<<<gRows, 256, 0, stream>>>(agg, W_neigh2, W_in2, bias2, dinv, t, agg, N);
  k_gather_out<<<gNode, 256, 0, stream>>>(csr_row, ptr, indeg, dinv, t, agg,
                                          W_out, b_out, out, N);
}